// Round 9
// baseline (5116.219 us; speedup 1.0000x reference)
//
#include <hip/hip_runtime.h>
#include <hip/hip_bf16.h>

typedef __bf16 bf16x8 __attribute__((ext_vector_type(8)));
typedef float f32x4 __attribute__((ext_vector_type(4)));
typedef unsigned int u32x4 __attribute__((ext_vector_type(4)));
typedef unsigned short u16;
typedef unsigned int u32;
typedef unsigned long long u64;

#define SLOT_TICKS 250ULL   // 2.5 us @ 100 MHz realtime clock
#define T0_LEAD    4000ULL  // 40 us startup headroom

// ---------- helpers ----------
__device__ __forceinline__ u16 f2bf(float f) {
  union { float f; unsigned int i; } c;
  c.f = f;
  unsigned int x = c.i;
  return (u16)((x + 0x7fffu + ((x >> 16) & 1u)) >> 16);  // RNE
}
__device__ __forceinline__ float sigm(float x) { return 1.f / (1.f + __expf(-x)); }
__device__ __forceinline__ float tanh_fast(float x) {
  float e2 = __expf(2.f * x);
  return 1.f - 2.f / (e2 + 1.f);
}

// ---------- x: [N=64][T=512][d=512] f32 -> [T][N][d] bf16 ; init h ring + flags + t0 ----------
// h ring: [2][64][512] u32 (u32 = 2 bf16 cols, low-elem LSB = half-step parity tag).
// buf0 first polled at s=2 (par 1) -> init LSB 0 ; buf1 at s=1 (par 0) -> init LSB 1.
__global__ void cvt_x_transpose(const float* __restrict__ in, u16* __restrict__ out,
                                u32* __restrict__ hbuf_u, u32* __restrict__ flags,
                                u64* __restrict__ t0buf) {
  int gid = blockIdx.x * blockDim.x + threadIdx.x;
  if (gid < 65536) hbuf_u[gid] = (gid < 32768) ? 0u : 1u;
  if (gid < 512) flags[gid] = 0u;
  if (gid == 0) t0buf[0] = 0ULL;
  if (gid >= 64 * 512 * 64) return;
  int k8 = gid & 63, t = (gid >> 6) & 511, n = gid >> 15;
  const float* src = in + ((size_t)(n * 512 + t) << 9) + (k8 << 3);
  float4 a = reinterpret_cast<const float4*>(src)[0];
  float4 b = reinterpret_cast<const float4*>(src)[1];
  union { u16 u[8]; uint4 d; } o;
  o.u[0] = f2bf(a.x); o.u[1] = f2bf(a.y); o.u[2] = f2bf(a.z); o.u[3] = f2bf(a.w);
  o.u[4] = f2bf(b.x); o.u[5] = f2bf(b.y); o.u[6] = f2bf(b.z); o.u[7] = f2bf(b.w);
  *reinterpret_cast<uint4*>(out + ((size_t)(t * 64 + n) << 9) + (k8 << 3)) = o.d;
}

// ---------- persistent LSTM: 128 blocks x 256 threads, 8 units/block ----------
// Block b owns units j0=b*8..+7 (32 gate rows, row l = g*8+u); wave w owns rows m0=w*16.
// h exchange: packed bf16 pairs + parity tag (correctness). Step pacing: device-global
// realtime clock slots (hint). Retry: 2KB flag poll (hint) then tagged reload.
__global__ void __launch_bounds__(256, 1) lstm_seq(
    const u16* __restrict__ xb,     // [512][64][512] bf16
    const float* __restrict__ w_ih, // [4096][512] f32
    const float* __restrict__ w_hh, // [4096][1024] f32
    u32* __restrict__ hbuf_u,       // [2][64][512] u32 (2 bf16/word, tagged)
    float* __restrict__ hTf,        // [64][1024] f32
    u32* __restrict__ flags,        // [512] per-wave hint flags
    u64* __restrict__ t0buf,        // common slot-clock origin
    const float* __restrict__ b_ih, const float* __restrict__ b_hh) {
  __shared__ u16 wh[32][1040];     // bank-conflict-padded
  __shared__ u16 wi[32][528];

  int b = blockIdx.x, t = threadIdx.x;
  int j0 = b << 3;

  // stage weight slices straight from f32 (once)
  for (int idx = t; idx < 32 * 128; idx += 256) {
    int l = idx >> 7, c8 = idx & 127;
    int gr = ((l >> 3) << 10) + j0 + (l & 7);
    const float* src = w_hh + ((size_t)gr << 10) + c8 * 8;
    float4 a = reinterpret_cast<const float4*>(src)[0];
    float4 c = reinterpret_cast<const float4*>(src)[1];
    union { u16 u[8]; bf16x8 v; } o;
    o.u[0] = f2bf(a.x); o.u[1] = f2bf(a.y); o.u[2] = f2bf(a.z); o.u[3] = f2bf(a.w);
    o.u[4] = f2bf(c.x); o.u[5] = f2bf(c.y); o.u[6] = f2bf(c.z); o.u[7] = f2bf(c.w);
    *(bf16x8*)(&wh[l][c8 * 8]) = o.v;
  }
  for (int idx = t; idx < 32 * 64; idx += 256) {
    int l = idx >> 6, c8 = idx & 63;
    int gr = ((l >> 3) << 10) + j0 + (l & 7);
    const float* src = w_ih + ((size_t)gr << 9) + c8 * 8;
    float4 a = reinterpret_cast<const float4*>(src)[0];
    float4 c = reinterpret_cast<const float4*>(src)[1];
    union { u16 u[8]; bf16x8 v; } o;
    o.u[0] = f2bf(a.x); o.u[1] = f2bf(a.y); o.u[2] = f2bf(a.z); o.u[3] = f2bf(a.w);
    o.u[4] = f2bf(c.x); o.u[5] = f2bf(c.y); o.u[6] = f2bf(c.z); o.u[7] = f2bf(c.w);
    *(bf16x8*)(&wi[l][c8 * 8]) = o.v;
  }
  __syncthreads();   // weights staged

  // ---- one-time slot-clock origin exchange ----
  if (b == 0 && t == 0) {
    u64 v = __builtin_amdgcn_s_memrealtime() + T0_LEAD;
    __hip_atomic_store(t0buf, v, __ATOMIC_RELAXED, __HIP_MEMORY_SCOPE_AGENT);
  }
  u64 t0;
  {
    int guard = 0;
    do {
      t0 = __hip_atomic_load(t0buf, __ATOMIC_RELAXED, __HIP_MEMORY_SCOPE_AGENT);
      if (t0) break;
      __builtin_amdgcn_s_sleep(2);
    } while (++guard < (1 << 22));
  }

  int lane = t & 63, wave = t >> 6;
  int m0 = wave << 4;
  int lr = lane & 15, hi = lane >> 4, lk8 = hi << 3;
  int u = lane & 7;
  int wgid = (b << 2) + wave;

  float bi_r = b_ih[j0 + u]        + b_hh[j0 + u];
  float bf_r = b_ih[1024 + j0 + u] + b_hh[1024 + j0 + u];
  float bg_r = b_ih[2048 + j0 + u] + b_hh[2048 + j0 + u];
  float bo_r = b_ih[3072 + j0 + u] + b_hh[3072 + j0 + u];
  float c_[4] = {0.f, 0.f, 0.f, 0.f};

  f32x4 acc[2];
  auto xgemm = [&](int step) {
    acc[0] = (f32x4){0.f, 0.f, 0.f, 0.f};
    acc[1] = (f32x4){0.f, 0.f, 0.f, 0.f};
    const u16* xbase = xb + ((size_t)step << 15) + ((m0 + lr) << 9) + lk8;
#pragma unroll
    for (int kk = 0; kk < 16; ++kk) {
      bf16x8 a = *(const bf16x8*)(xbase + kk * 32);
      bf16x8 w0 = *(const bf16x8*)(&wi[lr][kk * 32 + lk8]);
      bf16x8 w1 = *(const bf16x8*)(&wi[16 + lr][kk * 32 + lk8]);
      acc[0] = __builtin_amdgcn_mfma_f32_16x16x32_bf16(a, w0, acc[0], 0, 0, 0);
      acc[1] = __builtin_amdgcn_mfma_f32_16x16x32_bf16(a, w1, acc[1], 0, 0, 0);
    }
  };

  // wait for common start, then kick off
  while (__builtin_amdgcn_s_memrealtime() < t0) __builtin_amdgcn_s_sleep(1);
  xgemm(0);

  for (int s = 0; s < 512; ++s) {
    if (s > 0) {
      const u32* hbase = hbuf_u + ((s & 1) << 15) + ((m0 + lr) << 9) + (hi << 2);
      u32 par = (u32)((s >> 1) & 1);
      u32x4 ha[32];

      auto tryload = [&]() -> bool {   // tagged 32KB load; true if all tags match
#define LDH(OFF) asm volatile("global_load_dwordx4 %0, %1, off offset:" #OFF " sc0 sc1" \
                              : "=v"(ha[OFF / 64]) : "v"(hbase) : "memory");
        LDH(0) LDH(64) LDH(128) LDH(192) LDH(256) LDH(320) LDH(384) LDH(448)
        LDH(512) LDH(576) LDH(640) LDH(704) LDH(768) LDH(832) LDH(896) LDH(960)
        LDH(1024) LDH(1088) LDH(1152) LDH(1216) LDH(1280) LDH(1344) LDH(1408) LDH(1472)
        LDH(1536) LDH(1600) LDH(1664) LDH(1728) LDH(1792) LDH(1856) LDH(1920) LDH(1984)
#undef LDH
        asm volatile("s_waitcnt vmcnt(0)" ::: "memory");
        __builtin_amdgcn_sched_barrier(0);          // rule #18: fence reg consumers
        u32 ok;
        if (par) {
          u32 r = 0xFFFFFFFFu;
#pragma unroll
          for (int i2 = 0; i2 < 32; ++i2)
            r &= (ha[i2][0] & ha[i2][1]) & (ha[i2][2] & ha[i2][3]);
          ok = r & 1u;
        } else {
          u32 r = 0u;
#pragma unroll
          for (int i2 = 0; i2 < 32; ++i2)
            r |= (ha[i2][0] | ha[i2][1]) | (ha[i2][2] | ha[i2][3]);
          ok = (~r) & 1u;
        }
        return __all((int)ok) != 0;
      };

      // clock gate (pure SALU, no fabric traffic): don't probe before slot s
      {
        u64 tgt = t0 + (u64)s * SLOT_TICKS;
        while (__builtin_amdgcn_s_memrealtime() < tgt) __builtin_amdgcn_s_sleep(0);
      }

      if (!tryload()) {
        // retry: poll cheap 2KB hint flags until min >= s, then reload (tag-checked)
        const u32* fb = flags + (lane << 3);
        u32 tgt = (u32)s;
        int guard = 0;
        bool dead = false;
        do {
          while (true) {
            u32x4 f0, f1;
            asm volatile("global_load_dwordx4 %0, %2, off sc0 sc1\n\t"
                         "global_load_dwordx4 %1, %2, off offset:16 sc0 sc1\n\t"
                         "s_waitcnt vmcnt(0)"
                         : "=v"(f0), "=v"(f1) : "v"(fb) : "memory");
            __builtin_amdgcn_sched_barrier(0);
            u32 mn = f0[0];
            mn = mn < f0[1] ? mn : f0[1];
            mn = mn < f0[2] ? mn : f0[2];
            mn = mn < f0[3] ? mn : f0[3];
            mn = mn < f1[0] ? mn : f1[0];
            mn = mn < f1[1] ? mn : f1[1];
            mn = mn < f1[2] ? mn : f1[2];
            mn = mn < f1[3] ? mn : f1[3];
            if (__all((int)(mn >= tgt))) break;
            if (++guard > (1 << 22)) { dead = true; break; }   // fail loud, never hang
            __builtin_amdgcn_s_sleep(1);
          }
          if (dead) break;
        } while (!tryload());
      }

      __builtin_amdgcn_sched_barrier(0);
      // h-GEMM: ha IS bf16 A-data
#pragma unroll
      for (int kk = 0; kk < 32; ++kk) {
        union { u32x4 u; bf16x8 v; } af; af.u = ha[kk];
        bf16x8 w0 = *(const bf16x8*)(&wh[lr][kk * 32 + lk8]);
        bf16x8 w1 = *(const bf16x8*)(&wh[16 + lr][kk * 32 + lk8]);
        acc[0] = __builtin_amdgcn_mfma_f32_16x16x32_bf16(af.v, w0, acc[0], 0, 0, 0);
        acc[1] = __builtin_amdgcn_mfma_f32_16x16x32_bf16(af.v, w1, acc[1], 0, 0, 0);
      }
    }

    // pointwise cell update (lane pairs via shfl_xor 8); h(s+1) -> packed bf16 + tag
    u32 par1 = (u32)(((s + 1) >> 1) & 1);
    u32* hw_u = hbuf_u + (((s + 1) & 1) << 15);
#pragma unroll
    for (int q = 0; q < 4; ++q) {
      float a0 = acc[0][q], a1 = acc[1][q];
      float p0 = __shfl_xor(a0, 8, 64);   // f-gate partner
      float p1 = __shfl_xor(a1, 8, 64);   // o-gate partner
      float hv = 0.f;
      if (lr < 8) {
        float gi = a0 + bi_r, gf = p0 + bf_r, gg = a1 + bg_r, go = p1 + bo_r;
        float ii = sigm(gi), ff = sigm(gf), tg = tanh_fast(gg), oo = sigm(go);
        float cn = ff * c_[q] + ii * tg;
        c_[q] = cn;
        hv = oo * tanh_fast(cn);
      }
      if (s == 511) {
        if (lr < 8) hTf[((m0 + (hi << 2) + q) << 10) + j0 + u] = hv;
      } else {
        u32 hb = (u32)f2bf(hv);
        u32 pn = (u32)__shfl_xor((int)hb, 1, 64);   // partner column (lr^1)
        if (lr < 8 && !(lr & 1)) {
          u32 w = ((hb & ~1u) | par1) | (pn << 16);
          u32* dst = hw_u + ((m0 + (hi << 2) + q) << 9) + (j0 >> 1) + (lr >> 1);
          asm volatile("global_store_dword %0, %1, off sc0 sc1" :: "v"(dst), "v"(w) : "memory");
        }
      }
    }

    if (s < 511) {
      // hint flag: no drain needed — tags carry correctness
      if (lane == 0) {
        u32 v = (u32)(s + 1);
        asm volatile("global_store_dword %0, %1, off sc0 sc1" :: "v"(flags + wgid), "v"(v) : "memory");
      }
      xgemm(s + 1);   // overlaps h(s+1) fabric propagation
    }
  }
}

// ---------- FC head: block n computes out[n] ----------
__global__ void fc_head(const float* __restrict__ hTf, const float* __restrict__ fc_w,
                        const float* __restrict__ fc_b, float* __restrict__ out) {
  __shared__ float red[4];
  int n = blockIdx.x, t = threadIdx.x;
  float4 hv = *(const float4*)(hTf + (n << 10) + t * 4);
  float4 wv = *(const float4*)(fc_w + t * 4);
  float s = hv.x * wv.x + hv.y * wv.y + hv.z * wv.z + hv.w * wv.w;
#pragma unroll
  for (int o = 32; o; o >>= 1) s += __shfl_down(s, o, 64);
  if ((t & 63) == 0) red[t >> 6] = s;
  __syncthreads();
  if (t == 0) out[n] = sigm(red[0] + red[1] + red[2] + red[3] + fc_b[0]);
}

// ---------- launch ----------
extern "C" void kernel_launch(void* const* d_in, const int* in_sizes, int n_in,
                              void* d_out, int out_size, void* d_ws, size_t ws_size,
                              hipStream_t stream) {
  const float* x    = (const float*)d_in[0];
  const float* w_ih = (const float*)d_in[1];
  const float* w_hh = (const float*)d_in[2];
  const float* b_ih = (const float*)d_in[3];
  const float* b_hh = (const float*)d_in[4];
  const float* fc_w = (const float*)d_in[5];
  const float* fc_b = (const float*)d_in[6];
  float* out = (float*)d_out;

  char* ws = (char*)d_ws;
  u16*   xb     = (u16*)(ws);                  // 33,554,432 B
  u32*   hbuf_u = (u32*)(ws + 33554432);       //    262,144 B  [2][64][512] u32
  float* hTf    = (float*)(ws + 33816576);     //    262,144 B
  u32*   flags  = (u32*)(ws + 34078720);       //      2,048 B
  u64*   t0buf  = (u64*)(ws + 34080768);       //          8 B

  cvt_x_transpose<<<8192, 256, 0, stream>>>(x, xb, hbuf_u, flags, t0buf);
  lstm_seq<<<128, 256, 0, stream>>>(xb, w_ih, w_hh, hbuf_u, hTf, flags, t0buf, b_ih, b_hh);
  fc_head<<<64, 256, 0, stream>>>(hTf, fc_w, fc_b, out);
}

// Round 10
// 1529.181 us; speedup vs baseline: 3.3457x; 3.3457x over previous
//
#include <hip/hip_runtime.h>
#include <hip/hip_bf16.h>

typedef __bf16 bf16x8 __attribute__((ext_vector_type(8)));
typedef float f32x4 __attribute__((ext_vector_type(4)));
typedef unsigned int u32x4 __attribute__((ext_vector_type(4)));
typedef unsigned short u16;
typedef unsigned int u32;

// ---------- helpers ----------
__device__ __forceinline__ u16 f2bf(float f) {
  union { float f; unsigned int i; } c;
  c.f = f;
  unsigned int x = c.i;
  return (u16)((x + 0x7fffu + ((x >> 16) & 1u)) >> 16);  // RNE
}
__device__ __forceinline__ float sigm(float x) { return 1.f / (1.f + __expf(-x)); }
__device__ __forceinline__ float tanh_fast(float x) {
  float e2 = __expf(2.f * x);
  return 1.f - 2.f / (e2 + 1.f);
}

// ---------- fp32 -> bf16 (vectorized; for w_ih) ----------
__global__ void cvt_f32_bf16_v4(const float* __restrict__ in, u16* __restrict__ out, int n4) {
  int stride = gridDim.x * blockDim.x;
  for (int i = blockIdx.x * blockDim.x + threadIdx.x; i < n4; i += stride) {
    float4 v = reinterpret_cast<const float4*>(in)[i];
    union { u16 u[4]; uint2 d; } o;
    o.u[0] = f2bf(v.x); o.u[1] = f2bf(v.y); o.u[2] = f2bf(v.z); o.u[3] = f2bf(v.w);
    reinterpret_cast<uint2*>(out)[i] = o.d;
  }
}

// ---------- x: [N=64][T=512][d=512] f32 -> [T][N][d] bf16 ; init 4 group h rings ----------
// Per group: [2][16 rows][512 u32words] (u32 = 2 bf16 units, low-elem LSB = parity tag).
// buf0 first polled at s=2 (par 1) -> init LSB 0 ; buf1 at s=1 (par 0) -> init LSB 1.
__global__ void cvt_x_transpose(const float* __restrict__ in, u16* __restrict__ out,
                                u32* __restrict__ hbuf_u) {
  int gid = blockIdx.x * blockDim.x + threadIdx.x;
  if (gid < 65536) hbuf_u[gid] = ((gid >> 13) & 1) ? 1u : 0u;
  if (gid >= 64 * 512 * 64) return;
  int k8 = gid & 63, t = (gid >> 6) & 511, n = gid >> 15;
  const float* src = in + ((size_t)(n * 512 + t) << 9) + (k8 << 3);
  float4 a = reinterpret_cast<const float4*>(src)[0];
  float4 b = reinterpret_cast<const float4*>(src)[1];
  union { u16 u[8]; uint4 d; } o;
  o.u[0] = f2bf(a.x); o.u[1] = f2bf(a.y); o.u[2] = f2bf(a.z); o.u[3] = f2bf(a.w);
  o.u[4] = f2bf(b.x); o.u[5] = f2bf(b.y); o.u[6] = f2bf(b.z); o.u[7] = f2bf(b.w);
  *reinterpret_cast<uint4*>(out + ((size_t)(t * 64 + n) << 9) + (k8 << 3)) = o.d;
}

// ---------- batch-partitioned LSTM: 4 independent groups of 16 batch rows ----------
// 256 blocks x 256 threads. Block b: group grp=b&3 (rows 16grp..+15), slice sli=b>>2
// (units 16sli..+15 -> 64 gate rows, local row l = gate*16 + ul).
// w_hh slice bf16 in LDS (once); w_ih slice streamed (L2-resident). 4 waves split K.
// h exchange only within the 64-block group: packed-bf16 parity-tagged words.
__global__ void __launch_bounds__(256, 1) lstm_seq(
    const u16* __restrict__ xb,     // [512][64][512] bf16
    const u16* __restrict__ wib,    // [4096][512] bf16
    const float* __restrict__ w_hh, // [4096][1024] f32
    u32* __restrict__ hbuf_u,       // [4 grp][2][16][512] u32
    float* __restrict__ hTf,        // [64][1024] f32
    const float* __restrict__ b_ih, const float* __restrict__ b_hh) {
  __shared__ u16 wh[64][1032];      // 132,096 B; row l = gate*16 + ul
  __shared__ float gp[4][16][68];   // 17,408 B per-wave K-partial gates

  int blk = blockIdx.x, t = threadIdx.x;
  int grp = blk & 3, sli = blk >> 2;
  int u0 = sli << 4;

  // stage w_hh slice from f32 (once): local l -> global row (l>>4)*1024 + u0 + (l&15)
  for (int idx = t; idx < 64 * 128; idx += 256) {
    int l = idx >> 7, c8 = idx & 127;
    int gr = ((l >> 4) << 10) + u0 + (l & 15);
    const float* src = w_hh + ((size_t)gr << 10) + c8 * 8;
    float4 a = reinterpret_cast<const float4*>(src)[0];
    float4 c = reinterpret_cast<const float4*>(src)[1];
    union { u16 us[8]; bf16x8 v; } o;
    o.us[0] = f2bf(a.x); o.us[1] = f2bf(a.y); o.us[2] = f2bf(a.z); o.us[3] = f2bf(a.w);
    o.us[4] = f2bf(c.x); o.us[5] = f2bf(c.y); o.us[6] = f2bf(c.z); o.us[7] = f2bf(c.w);
    *(bf16x8*)(&wh[l][c8 * 8]) = o.v;
  }

  int lane = t & 63, wv = t >> 6;
  int lr = lane & 15, hi = lane >> 4, lk8 = hi << 3;

  // pointwise mapping: thread t -> (prow = t>>4, pul = t&15); c lives here
  int prow = t >> 4, pul = t & 15;
  float bI = b_ih[u0 + pul]        + b_hh[u0 + pul];
  float bF = b_ih[1024 + u0 + pul] + b_hh[1024 + u0 + pul];
  float bG = b_ih[2048 + u0 + pul] + b_hh[2048 + u0 + pul];
  float bO = b_ih[3072 + u0 + pul] + b_hh[3072 + u0 + pul];
  float c_ = 0.f;

  u32* hgrp = hbuf_u + (grp << 14);   // 2 bufs x 8192 words
  __syncthreads();                     // weights staged

  for (int s = 0; s < 512; ++s) {
    f32x4 acc[4] = {};   // 4 gate n-tiles

    // x-GEMM first (independent of h; overlaps other blocks' h production).
    // wave wv handles x K-quarter [128wv, 128wv+128)
    {
      const u16* xb_ = xb + ((size_t)s << 15) + (size_t)(((grp << 4) + lr) << 9) + (wv << 7) + lk8;
      const u16* wb_ = wib + ((size_t)(u0 + lr) << 9) + (wv << 7) + lk8;
#pragma unroll
      for (int ks = 0; ks < 4; ++ks) {
        bf16x8 a = *(const bf16x8*)(xb_ + ks * 32);
#pragma unroll
        for (int nt = 0; nt < 4; ++nt) {
          bf16x8 bfr = *(const bf16x8*)(wb_ + ((size_t)nt << 19) + ks * 32);
          acc[nt] = __builtin_amdgcn_mfma_f32_16x16x32_bf16(a, bfr, acc[nt], 0, 0, 0);
        }
      }
    }

    if (s > 0) {
      // poll-load h(s) K-quarter [256wv, 256wv+256): lane (lr,hi) -> row lr,
      // words 128wv + 4hi + 16ks + [0,4)  == its A-frags exactly
      const u32* hb4 = hgrp + ((s & 1) << 13) + (lr << 9) + (wv << 7) + (hi << 2);
      u32 par = (u32)((s >> 1) & 1);
      u32x4 ha[8];
      int tries = 0;
      while (true) {
#define LDH(OFF) asm volatile("global_load_dwordx4 %0, %1, off offset:" #OFF " sc0 sc1" \
                              : "=v"(ha[OFF / 64]) : "v"(hb4) : "memory");
        LDH(0) LDH(64) LDH(128) LDH(192) LDH(256) LDH(320) LDH(384) LDH(448)
#undef LDH
        asm volatile("s_waitcnt vmcnt(0)" ::: "memory");
        __builtin_amdgcn_sched_barrier(0);          // rule #18
        u32 ok;
        if (par) {
          u32 r = 0xFFFFFFFFu;
#pragma unroll
          for (int i2 = 0; i2 < 8; ++i2)
            r &= (ha[i2][0] & ha[i2][1]) & (ha[i2][2] & ha[i2][3]);
          ok = r & 1u;
        } else {
          u32 r = 0u;
#pragma unroll
          for (int i2 = 0; i2 < 8; ++i2)
            r |= (ha[i2][0] | ha[i2][1]) | (ha[i2][2] | ha[i2][3]);
          ok = (~r) & 1u;
        }
        if (__all((int)ok)) break;
        if (++tries > (1 << 20)) break;             // fail loud, never hang
        __builtin_amdgcn_s_sleep(1);
      }
      __builtin_amdgcn_sched_barrier(0);
      // h-GEMM over this wave's K-quarter (captured regs ARE the A-frags)
#pragma unroll
      for (int ks = 0; ks < 8; ++ks) {
        union { u32x4 uu; bf16x8 v; } af; af.uu = ha[ks];
#pragma unroll
        for (int nt = 0; nt < 4; ++nt) {
          bf16x8 bfr = *(const bf16x8*)(&wh[(nt << 4) + lr][(wv << 8) + ks * 32 + lk8]);
          acc[nt] = __builtin_amdgcn_mfma_f32_16x16x32_bf16(af.v, bfr, acc[nt], 0, 0, 0);
        }
      }
    }

    // per-wave K-partials -> LDS
#pragma unroll
    for (int nt = 0; nt < 4; ++nt)
#pragma unroll
      for (int q = 0; q < 4; ++q)
        gp[wv][(hi << 2) + q][(nt << 4) + lr] = acc[nt][q];
    __syncthreads();

    // pointwise: reduce 4 wave-partials, cell update, emit h
    float g0 = gp[0][prow][pul]      + gp[1][prow][pul]      + gp[2][prow][pul]      + gp[3][prow][pul]      + bI;
    float g1 = gp[0][prow][16 + pul] + gp[1][prow][16 + pul] + gp[2][prow][16 + pul] + gp[3][prow][16 + pul] + bF;
    float g2 = gp[0][prow][32 + pul] + gp[1][prow][32 + pul] + gp[2][prow][32 + pul] + gp[3][prow][32 + pul] + bG;
    float g3 = gp[0][prow][48 + pul] + gp[1][prow][48 + pul] + gp[2][prow][48 + pul] + gp[3][prow][48 + pul] + bO;
    float ii = sigm(g0), ff = sigm(g1), tg = tanh_fast(g2), oo = sigm(g3);
    float cn = ff * c_ + ii * tg;
    c_ = cn;
    float hv = oo * tanh_fast(cn);
    if (s == 511) {
      hTf[((size_t)((grp << 4) + prow) << 10) + u0 + pul] = hv;  // plain; kernel-end flush
    } else {
      u32 hb = (u32)f2bf(hv);
      u32 pn = (u32)__shfl_xor((int)hb, 1, 64);     // partner unit (pul^1), same wave
      if (!(pul & 1)) {
        u32 par1 = (u32)(((s + 1) >> 1) & 1);
        u32 wdat = ((hb & ~1u) | par1) | (pn << 16);
        u32* dst = hgrp + (((s + 1) & 1) << 13) + (prow << 9) + (sli << 3) + (pul >> 1);
        asm volatile("global_store_dword %0, %1, off sc0 sc1" :: "v"(dst), "v"(wdat) : "memory");
      }
    }
    __syncthreads();   // protect gp before next step's rewrite
  }
}

// ---------- FC head: block n computes out[n] ----------
__global__ void fc_head(const float* __restrict__ hTf, const float* __restrict__ fc_w,
                        const float* __restrict__ fc_b, float* __restrict__ out) {
  __shared__ float red[4];
  int n = blockIdx.x, t = threadIdx.x;
  float4 hv = *(const float4*)(hTf + (n << 10) + t * 4);
  float4 wv = *(const float4*)(fc_w + t * 4);
  float s = hv.x * wv.x + hv.y * wv.y + hv.z * wv.z + hv.w * wv.w;
#pragma unroll
  for (int o = 32; o; o >>= 1) s += __shfl_down(s, o, 64);
  if ((t & 63) == 0) red[t >> 6] = s;
  __syncthreads();
  if (t == 0) out[n] = sigm(red[0] + red[1] + red[2] + red[3] + fc_b[0]);
}

// ---------- launch ----------
extern "C" void kernel_launch(void* const* d_in, const int* in_sizes, int n_in,
                              void* d_out, int out_size, void* d_ws, size_t ws_size,
                              hipStream_t stream) {
  const float* x    = (const float*)d_in[0];
  const float* w_ih = (const float*)d_in[1];
  const float* w_hh = (const float*)d_in[2];
  const float* b_ih = (const float*)d_in[3];
  const float* b_hh = (const float*)d_in[4];
  const float* fc_w = (const float*)d_in[5];
  const float* fc_b = (const float*)d_in[6];
  float* out = (float*)d_out;

  char* ws = (char*)d_ws;
  u16*   xb     = (u16*)(ws);                  // 33,554,432 B
  u16*   wib    = (u16*)(ws + 33554432);       //  4,194,304 B
  u32*   hbuf_u = (u32*)(ws + 37748736);       //    262,144 B  [4][2][16][512] u32
  float* hTf    = (float*)(ws + 38010880);     //    262,144 B

  cvt_x_transpose<<<8192, 256, 0, stream>>>(x, xb, hbuf_u);
  cvt_f32_bf16_v4<<<512, 256, 0, stream>>>(w_ih, wib, 2097152 / 4);
  lstm_seq<<<256, 256, 0, stream>>>(xb, wib, w_hh, hbuf_u, hTf, b_ih, b_hh);
  fc_head<<<64, 256, 0, stream>>>(hTf, fc_w, fc_b, out);
}